// Round 9
// baseline (285.814 us; speedup 1.0000x reference)
//
#include <hip/hip_runtime.h>
#include <math.h>

// MoE gate: B=4, S=4096, H=2048, E=64, top-2, seq_aux loss.
// d_out layout (float): topk_idx [16384*2] | topk_weight [16384*2] | aux_loss [1]
//
// v10: v9 with ONE change: __launch_bounds__(512,8) -> (512,6).
//  Evidence (v7+v9): the (512,8) 64-reg budget on gfx950's UNIFIED VGPR/AGPR file
//  splits ~32 arch + 32 acc -> allocator reports VGPR=32 and spills 26-103 MB to
//  scratch (WRITE_SIZE blowup), gemm 128-157us. (512,6) caps at ~84 regs; true
//  demand ~55-70 unified fits with margin at 24 waves/CU (75% of HW max).
//  Screen (unchanged, passed r8): 2-term split (A = ah+al exact to 2^-16, B rounded
//  bf16); gap-diff sigma 9.2e-4, TAU = 8e-3 = 8.7 sigma. fp64 re-rank absorbs
//  flagged ~10-13%.
//  K1 prep_b:    pack W to MFMA B-frags (bf16 rounded) + zero aux accums.
//  K2 gemm_gate: 2-term screening GEMM + fused gate/top-3/aux + inline fp64 re-rank.
//  K3 finalize:  1 block, reduces replicated accumulators -> aux_loss.

#define TT 16384
#define HH 2048
#define EE 64
#define BB 4
#define M_TOK 16   // tokens per block
#define TAU 8e-3f  // gap threshold: 8.7 sigma of 2-term screening gap error
#define NREP 8     // atomic replication for aux accumulators
#define NBLK (TT / M_TOK)   // 1024

typedef float v4f __attribute__((ext_vector_type(4)));
typedef float f4v __attribute__((ext_vector_type(4)));
typedef short s8v __attribute__((ext_vector_type(8)));
typedef int   i4v __attribute__((ext_vector_type(4)));

__device__ __forceinline__ unsigned short f2bf(float f) {
    unsigned u = __float_as_uint(f);
    return (unsigned short)((u + 0x7fffu + ((u >> 16) & 1u)) >> 16);
}

// 2-term split of two floats: hi = packed truncated bf16 pair, lo = packed bf16
// of the exact residuals (f - hi); residual trunc error <= 2^-16 * |f|.
__device__ __forceinline__ void split2(float f0, float f1, unsigned& hi, unsigned& lo) {
    unsigned u0 = __float_as_uint(f0), u1 = __float_as_uint(f1);
    unsigned m0 = u0 & 0xffff0000u,    m1 = u1 & 0xffff0000u;
    hi = (u0 >> 16) | m1;                                        // v_perm
    float l0 = f0 - __uint_as_float(m0);                         // exact
    float l1 = f1 - __uint_as_float(m1);
    lo = (__float_as_uint(l0) >> 16) | (__float_as_uint(l1) & 0xffff0000u);
}
__device__ __forceinline__ s8v pack4(unsigned a, unsigned b, unsigned c, unsigned d) {
    i4v t = {(int)a, (int)b, (int)c, (int)d};
    return __builtin_bit_cast(s8v, t);
}

// Pre-pack W[E][H] into MFMA B-fragment order, bf16 (rounded):
// b[nt][ks64][lane][j] = w[nt*16 + (lane&15)][ks64*32 + (lane>>4)*8 + j]
// Block 0 also zeroes the replicated aux accumulators (stream order covers K2).
__global__ void prep_b(const float* __restrict__ w,
                       unsigned short* __restrict__ bhi,
                       float* __restrict__ zreg) {
    if (blockIdx.x == 0) {
        for (int i = threadIdx.x; i < 2 * NREP * BB * EE; i += 256) zreg[i] = 0.f;
    }
    int idx = blockIdx.x * blockDim.x + threadIdx.x;   // 0..131071
    int j    = idx & 7;
    int lane = (idx >> 3) & 63;
    int ks   = (idx >> 9) & 63;
    int nt   = idx >> 15;
    int e = nt * 16 + (lane & 15);
    int k = ks * 32 + (lane >> 4) * 8 + j;
    bhi[idx] = f2bf(w[e * HH + k]);
}

// ---------------- K2: 2-term screening GEMM (24 waves/CU, no spill) + gate + rerank ----------------
__global__ __launch_bounds__(512, 6) void gemm_gate(
    const float* __restrict__ x,
    const unsigned short* __restrict__ bhi,
    const float* __restrict__ w,
    float* __restrict__ out_idx, float* __restrict__ out_w,
    float* __restrict__ g_cnt, float* __restrict__ g_ssum) {

    __shared__ float lg[M_TOK][68];                // logit tile, padded (~4.3 KB)
    __shared__ float bssum[EE];                    // per-expert score sums
    __shared__ float bcnt[EE];                     // per-expert top-2 counts
    __shared__ int   fl[M_TOK];                    // flagged-token list (local rows)
    __shared__ int   fl_cnt;

    const int tid   = threadIdx.x;
    const int wavei = tid >> 6;                 // 0..7 = K-eighth owner
    const int lane  = tid & 63;
    const int tok0  = blockIdx.x * M_TOK;

    // zero lg (reduction target) + small init
    for (int i = tid; i < M_TOK * 68; i += 512) (&lg[0][0])[i] = 0.f;
    if (tid < EE) { bssum[tid] = 0.f; bcnt[tid] = 0.f; }
    if (tid == 0) fl_cnt = 0;

    // A: lane reads row (lane&15), k = wavei*256 + ks*32 + (lane>>4)*8 + j (contiguous 8)
    const float* __restrict__ xp =
        x + (size_t)(tok0 + (lane & 15)) * HH + wavei * 256 + (lane >> 4) * 8;
    // B: shorts at ((nt*64 + wavei*8 + ks)*64 + lane)*8 ; nt stride 32768, ks stride 512
    const unsigned short* __restrict__ bhp = bhi + ((size_t)(wavei * 8) * 64 + lane) * 8;

    f4v acc[4];
#pragma unroll
    for (int nt = 0; nt < 4; ++nt) acc[nt] = f4v{0.f, 0.f, 0.f, 0.f};

#pragma unroll
    for (int ks = 0; ks < 8; ++ks) {
        v4f xa = *(const v4f*)(xp + ks * 32);
        v4f xb = *(const v4f*)(xp + ks * 32 + 4);
        unsigned h01, l01, h23, l23, h45, l45, h67, l67;
        split2(xa.x, xa.y, h01, l01);
        split2(xa.z, xa.w, h23, l23);
        split2(xb.x, xb.y, h45, l45);
        split2(xb.z, xb.w, h67, l67);
        s8v ah = pack4(h01, h23, h45, h67);
        s8v al = pack4(l01, l23, l45, l67);
        // B in two pairs to cap live registers
        {
            s8v b0 = *(const s8v*)(bhp + ks * 512);
            s8v b1 = *(const s8v*)(bhp + 32768 + ks * 512);
            acc[0] = __builtin_amdgcn_mfma_f32_16x16x32_bf16(ah, b0, acc[0], 0, 0, 0);
            acc[0] = __builtin_amdgcn_mfma_f32_16x16x32_bf16(al, b0, acc[0], 0, 0, 0);
            acc[1] = __builtin_amdgcn_mfma_f32_16x16x32_bf16(ah, b1, acc[1], 0, 0, 0);
            acc[1] = __builtin_amdgcn_mfma_f32_16x16x32_bf16(al, b1, acc[1], 0, 0, 0);
        }
        {
            s8v b2 = *(const s8v*)(bhp + 2 * 32768 + ks * 512);
            s8v b3 = *(const s8v*)(bhp + 3 * 32768 + ks * 512);
            acc[2] = __builtin_amdgcn_mfma_f32_16x16x32_bf16(ah, b2, acc[2], 0, 0, 0);
            acc[2] = __builtin_amdgcn_mfma_f32_16x16x32_bf16(al, b2, acc[2], 0, 0, 0);
            acc[3] = __builtin_amdgcn_mfma_f32_16x16x32_bf16(ah, b3, acc[3], 0, 0, 0);
            acc[3] = __builtin_amdgcn_mfma_f32_16x16x32_bf16(al, b3, acc[3], 0, 0, 0);
        }
    }

    __syncthreads();                            // lg zeroed (and all waves done)

    // ---- K-reduction: ds_add_f32 into lg ----
    // C-layout per nt: col = nt*16 + (lane&15), row = (lane>>4)*4 + r
    {
        const int r0 = (lane >> 4) * 4;
        const int c  = lane & 15;
#pragma unroll
        for (int nt = 0; nt < 4; ++nt)
#pragma unroll
            for (int r = 0; r < 4; ++r)
                atomicAdd(&lg[r0 + r][nt * 16 + c], acc[nt][r]);
    }
    __syncthreads();                            // lg complete

    // ---- fused gate: each wave handles 2 tokens, lane = expert ----
    float ssum_l = 0.f;                         // per-expert softmax-score sum (2 tokens)

#pragma unroll
    for (int r = 0; r < 2; ++r) {
        const int tl = wavei * 2 + r;
        const int t  = tok0 + tl;
        float l = lg[tl][lane];

        // softmax score (fp32, feeds aux only)
        float mx = l;
#pragma unroll
        for (int off = 32; off; off >>= 1) mx = fmaxf(mx, __shfl_xor(mx, off, 64));
        float p = __expf(l - mx);
        float Z = p;
#pragma unroll
        for (int off = 32; off; off >>= 1) Z += __shfl_xor(Z, off, 64);
        ssum_l += p / Z;

        // top-3 by screened logit (tie -> lower index); cl[2] only feeds the flag
        float v = l;
        int cand[3]; float cl[3];
#pragma unroll
        for (int q = 0; q < 3; ++q) {
            float bv = v; int bi = lane;
#pragma unroll
            for (int off = 32; off; off >>= 1) {
                float ov = __shfl_xor(bv, off, 64);
                int   oi = __shfl_xor(bi, off, 64);
                if (ov > bv || (ov == bv && oi < bi)) { bv = ov; bi = oi; }
            }
            cand[q] = bi; cl[q] = bv;
            if (lane == bi) v = -3.4e38f;
        }

        if (lane == 0) {
            atomicAdd(&bcnt[cand[0]], 1.f);      // LDS atomics, trivial
            atomicAdd(&bcnt[cand[1]], 1.f);
            float w1 = 1.f / (1.f + __expf(cl[1] - cl[0]));  // softmax denom cancels
            out_idx[t * 2]     = (float)cand[0];
            out_idx[t * 2 + 1] = (float)cand[1];
            out_w[t * 2]       = w1;
            out_w[t * 2 + 1]   = 1.f - w1;
            if (cl[0] - cl[1] < TAU || cl[1] - cl[2] < TAU) {
                int pos = atomicAdd(&fl_cnt, 1);
                fl[pos] = tl;
            }
        }
    }

    atomicAdd(&bssum[lane], ssum_l);            // 8 waves -> LDS
    __syncthreads();                            // bcnt/bssum/fl complete

    // ---- publish per-block partials: ONE relaxed atomicAdd per expert ----
    {
        const int b   = tok0 >> 12;             // block-uniform batch index
        const int rep = (blockIdx.x & (NREP - 1)) * (BB * EE);
        if (tid < EE)
            atomicAdd(&g_cnt[rep + b * EE + tid], bcnt[tid]);
        else if (tid < 2 * EE)
            atomicAdd(&g_ssum[rep + b * EE + (tid - EE)], bssum[tid - EE]);
    }

    // ---- inline fp64 exact re-rank of this block's flagged tokens (~1.8/block) ----
    const int nfl = fl_cnt;
    for (int i = wavei; i < nfl; i += 8) {
        const int tl = fl[i];
        const int t  = tok0 + tl;
        float l = lg[tl][lane];

        float v = l;
        int cand4[4];
#pragma unroll
        for (int q = 0; q < 4; ++q) {
            float bv = v; int bi = lane;
#pragma unroll
            for (int off = 32; off; off >>= 1) {
                float ov = __shfl_xor(bv, off, 64);
                int   oi = __shfl_xor(bi, off, 64);
                if (ov > bv || (ov == bv && oi < bi)) { bv = ov; bi = oi; }
            }
            cand4[q] = bi;
            if (lane == bi) v = -3.4e38f;
        }

        const float* __restrict__ xt  = x + (size_t)t * HH;          // L2-hot
        const float* __restrict__ w0p = w + (size_t)cand4[0] * HH;
        const float* __restrict__ w1p = w + (size_t)cand4[1] * HH;
        const float* __restrict__ w2p = w + (size_t)cand4[2] * HH;
        const float* __restrict__ w3p = w + (size_t)cand4[3] * HH;
        double d0 = 0.0, d1 = 0.0, d2 = 0.0, d3 = 0.0;
#pragma unroll
        for (int ii = 0; ii < 8; ++ii) {
            const int k = ii * 256 + lane * 4;
            v4f xv = *(const v4f*)(xt + k);
            v4f a0 = *(const v4f*)(w0p + k);
            v4f a1 = *(const v4f*)(w1p + k);
            v4f a2 = *(const v4f*)(w2p + k);
            v4f a3 = *(const v4f*)(w3p + k);
            double dx0 = (double)xv.x, dx1 = (double)xv.y;
            double dx2 = (double)xv.z, dx3 = (double)xv.w;
            d0 = fma(dx0, (double)a0.x, d0); d0 = fma(dx1, (double)a0.y, d0);
            d0 = fma(dx2, (double)a0.z, d0); d0 = fma(dx3, (double)a0.w, d0);
            d1 = fma(dx0, (double)a1.x, d1); d1 = fma(dx1, (double)a1.y, d1);
            d1 = fma(dx2, (double)a1.z, d1); d1 = fma(dx3, (double)a1.w, d1);
            d2 = fma(dx0, (double)a2.x, d2); d2 = fma(dx1, (double)a2.y, d2);
            d2 = fma(dx2, (double)a2.z, d2); d2 = fma(dx3, (double)a2.w, d2);
            d3 = fma(dx0, (double)a3.x, d3); d3 = fma(dx1, (double)a3.y, d3);
            d3 = fma(dx2, (double)a3.z, d3); d3 = fma(dx3, (double)a3.w, d3);
        }
#pragma unroll
        for (int off = 32; off; off >>= 1) {
            d0 += __shfl_xor(d0, off, 64);
            d1 += __shfl_xor(d1, off, 64);
            d2 += __shfl_xor(d2, off, 64);
            d3 += __shfl_xor(d3, off, 64);
        }

        double bd[4] = {d0, d1, d2, d3};
        int e1 = cand4[0]; double l1 = bd[0];
#pragma unroll
        for (int q = 1; q < 4; ++q)
            if (bd[q] > l1 || (bd[q] == l1 && cand4[q] < e1)) { l1 = bd[q]; e1 = cand4[q]; }
        int e2 = -1; double l2 = -1e300;
#pragma unroll
        for (int q = 0; q < 4; ++q) {
            if (cand4[q] == e1) continue;
            if (e2 < 0 || bd[q] > l2 || (bd[q] == l2 && cand4[q] < e2)) { l2 = bd[q]; e2 = cand4[q]; }
        }

        double w1d = 1.0 / (1.0 + exp(l2 - l1));
        if (lane == 0) {
            out_idx[t * 2]     = (float)e1;
            out_idx[t * 2 + 1] = (float)e2;
            out_w[t * 2]       = (float)w1d;
            out_w[t * 2 + 1]   = (float)(1.0 - w1d);
        }
    }
}

// aux = 0.01/(B * 128 * S) * sum_{b,e} cnt[b,e]*ssum[b,e]   (E/(S*K)=1/128)
__global__ void finalize(const float* __restrict__ g_cnt,
                         const float* __restrict__ g_ssum,
                         float* __restrict__ aux_out) {
    int lane = threadIdx.x;  // 64 threads, lane = expert
    float a = 0.f;
    for (int b = 0; b < BB; ++b) {
        float c = 0.f, ss = 0.f;
#pragma unroll
        for (int r = 0; r < NREP; ++r) {
            c  += g_cnt[r * (BB * EE) + b * EE + lane];
            ss += g_ssum[r * (BB * EE) + b * EE + lane];
        }
        a += c * ss;
    }
#pragma unroll
    for (int off = 32; off; off >>= 1) a += __shfl_xor(a, off, 64);
    if (lane == 0) aux_out[0] = a * (0.01f / (4.f * 128.f * 4096.f));
}

extern "C" void kernel_launch(void* const* d_in, const int* in_sizes, int n_in,
                              void* d_out, int out_size, void* d_ws, size_t ws_size,
                              hipStream_t stream) {
    const float* x = (const float*)d_in[0];   // [4,4096,2048]
    const float* w = (const float*)d_in[1];   // [64,2048]
    float* out = (float*)d_out;
    float* out_idx = out;                 // [16384*2]
    float* out_w   = out + 2 * TT;        // [16384*2]
    float* aux     = out + 4 * TT;        // [1]

    // ws layout
    unsigned short* bhi = (unsigned short*)d_ws;                    // 256 KB
    float* g_cnt  = (float*)(bhi + (size_t)EE * HH);                // 8 KB
    float* g_ssum = g_cnt + NREP * BB * EE;                         // 8 KB

    prep_b<<<(EE * HH) / 256, 256, 0, stream>>>(w, bhi, g_cnt);
    gemm_gate<<<NBLK, 512, 0, stream>>>(x, bhi, w, out_idx, out_w,
                                        g_cnt, g_ssum);
    finalize<<<1, 64, 0, stream>>>(g_cnt, g_ssum, aux);
}

// Round 10
// 273.866 us; speedup vs baseline: 1.0436x; 1.0436x over previous
//
#include <hip/hip_runtime.h>
#include <math.h>

// MoE gate: B=4, S=4096, H=2048, E=64, top-2, seq_aux loss.
// d_out layout (float): topk_idx [16384*2] | topk_weight [16384*2] | aux_loss [1]
//
// v11: v10 with ONE change: drop the launch_bounds occupancy clause.
//  Evidence (v7/v9/v10): ANY tight 2nd arg ((512,8)->VGPR32, (512,6)->VGPR40)
//  makes the allocator clamp arch-VGPRs below the nominal budget (unified-file
//  AGPR reservation double-counted) and spill 12-103 MB to scratch. Natural
//  allocation for this body is ~56 regs (v5/v6, zero spill) which ALREADY fits
//  the 64-reg bin for 8 waves/SIMD. Grid = 1024 blocks x 8 waves = 32 waves/CU.
//  Screen (unchanged, passed r8/r9): 2-term split (A = ah+al exact to 2^-16,
//  B rounded bf16); gap-diff sigma 9.2e-4, TAU = 8e-3 = 8.7 sigma. fp64 re-rank
//  absorbs flagged ~10-13%.
//  K1 prep_b:    pack W to MFMA B-frags (bf16 rounded) + zero aux accums.
//  K2 gemm_gate: 2-term screening GEMM + fused gate/top-3/aux + inline fp64 re-rank.
//  K3 finalize:  1 block, reduces replicated accumulators -> aux_loss.

#define TT 16384
#define HH 2048
#define EE 64
#define BB 4
#define M_TOK 16   // tokens per block
#define TAU 8e-3f  // gap threshold: 8.7 sigma of 2-term screening gap error
#define NREP 8     // atomic replication for aux accumulators
#define NBLK (TT / M_TOK)   // 1024

typedef float v4f __attribute__((ext_vector_type(4)));
typedef float f4v __attribute__((ext_vector_type(4)));
typedef short s8v __attribute__((ext_vector_type(8)));
typedef int   i4v __attribute__((ext_vector_type(4)));

__device__ __forceinline__ unsigned short f2bf(float f) {
    unsigned u = __float_as_uint(f);
    return (unsigned short)((u + 0x7fffu + ((u >> 16) & 1u)) >> 16);
}

// 2-term split of two floats: hi = packed truncated bf16 pair, lo = packed bf16
// of the exact residuals (f - hi); residual trunc error <= 2^-16 * |f|.
__device__ __forceinline__ void split2(float f0, float f1, unsigned& hi, unsigned& lo) {
    unsigned u0 = __float_as_uint(f0), u1 = __float_as_uint(f1);
    unsigned m0 = u0 & 0xffff0000u,    m1 = u1 & 0xffff0000u;
    hi = (u0 >> 16) | m1;                                        // v_perm
    float l0 = f0 - __uint_as_float(m0);                         // exact
    float l1 = f1 - __uint_as_float(m1);
    lo = (__float_as_uint(l0) >> 16) | (__float_as_uint(l1) & 0xffff0000u);
}
__device__ __forceinline__ s8v pack4(unsigned a, unsigned b, unsigned c, unsigned d) {
    i4v t = {(int)a, (int)b, (int)c, (int)d};
    return __builtin_bit_cast(s8v, t);
}

// Pre-pack W[E][H] into MFMA B-fragment order, bf16 (rounded):
// b[nt][ks64][lane][j] = w[nt*16 + (lane&15)][ks64*32 + (lane>>4)*8 + j]
// Block 0 also zeroes the replicated aux accumulators (stream order covers K2).
__global__ void prep_b(const float* __restrict__ w,
                       unsigned short* __restrict__ bhi,
                       float* __restrict__ zreg) {
    if (blockIdx.x == 0) {
        for (int i = threadIdx.x; i < 2 * NREP * BB * EE; i += 256) zreg[i] = 0.f;
    }
    int idx = blockIdx.x * blockDim.x + threadIdx.x;   // 0..131071
    int j    = idx & 7;
    int lane = (idx >> 3) & 63;
    int ks   = (idx >> 9) & 63;
    int nt   = idx >> 15;
    int e = nt * 16 + (lane & 15);
    int k = ks * 32 + (lane >> 4) * 8 + j;
    bhi[idx] = f2bf(w[e * HH + k]);
}

// ---------------- K2: 2-term screening GEMM (natural regalloc) + gate + rerank ----------------
__global__ __launch_bounds__(512) void gemm_gate(
    const float* __restrict__ x,
    const unsigned short* __restrict__ bhi,
    const float* __restrict__ w,
    float* __restrict__ out_idx, float* __restrict__ out_w,
    float* __restrict__ g_cnt, float* __restrict__ g_ssum) {

    __shared__ float lg[M_TOK][68];                // logit tile, padded (~4.3 KB)
    __shared__ float bssum[EE];                    // per-expert score sums
    __shared__ float bcnt[EE];                     // per-expert top-2 counts
    __shared__ int   fl[M_TOK];                    // flagged-token list (local rows)
    __shared__ int   fl_cnt;

    const int tid   = threadIdx.x;
    const int wavei = tid >> 6;                 // 0..7 = K-eighth owner
    const int lane  = tid & 63;
    const int tok0  = blockIdx.x * M_TOK;

    // zero lg (reduction target) + small init
    for (int i = tid; i < M_TOK * 68; i += 512) (&lg[0][0])[i] = 0.f;
    if (tid < EE) { bssum[tid] = 0.f; bcnt[tid] = 0.f; }
    if (tid == 0) fl_cnt = 0;

    // A: lane reads row (lane&15), k = wavei*256 + ks*32 + (lane>>4)*8 + j (contiguous 8)
    const float* __restrict__ xp =
        x + (size_t)(tok0 + (lane & 15)) * HH + wavei * 256 + (lane >> 4) * 8;
    // B: shorts at ((nt*64 + wavei*8 + ks)*64 + lane)*8 ; nt stride 32768, ks stride 512
    const unsigned short* __restrict__ bhp = bhi + ((size_t)(wavei * 8) * 64 + lane) * 8;

    f4v acc[4];
#pragma unroll
    for (int nt = 0; nt < 4; ++nt) acc[nt] = f4v{0.f, 0.f, 0.f, 0.f};

#pragma unroll
    for (int ks = 0; ks < 8; ++ks) {
        v4f xa = *(const v4f*)(xp + ks * 32);
        v4f xb = *(const v4f*)(xp + ks * 32 + 4);
        unsigned h01, l01, h23, l23, h45, l45, h67, l67;
        split2(xa.x, xa.y, h01, l01);
        split2(xa.z, xa.w, h23, l23);
        split2(xb.x, xb.y, h45, l45);
        split2(xb.z, xb.w, h67, l67);
        s8v ah = pack4(h01, h23, h45, h67);
        s8v al = pack4(l01, l23, l45, l67);
        // B in two pairs to cap live registers
        {
            s8v b0 = *(const s8v*)(bhp + ks * 512);
            s8v b1 = *(const s8v*)(bhp + 32768 + ks * 512);
            acc[0] = __builtin_amdgcn_mfma_f32_16x16x32_bf16(ah, b0, acc[0], 0, 0, 0);
            acc[0] = __builtin_amdgcn_mfma_f32_16x16x32_bf16(al, b0, acc[0], 0, 0, 0);
            acc[1] = __builtin_amdgcn_mfma_f32_16x16x32_bf16(ah, b1, acc[1], 0, 0, 0);
            acc[1] = __builtin_amdgcn_mfma_f32_16x16x32_bf16(al, b1, acc[1], 0, 0, 0);
        }
        {
            s8v b2 = *(const s8v*)(bhp + 2 * 32768 + ks * 512);
            s8v b3 = *(const s8v*)(bhp + 3 * 32768 + ks * 512);
            acc[2] = __builtin_amdgcn_mfma_f32_16x16x32_bf16(ah, b2, acc[2], 0, 0, 0);
            acc[2] = __builtin_amdgcn_mfma_f32_16x16x32_bf16(al, b2, acc[2], 0, 0, 0);
            acc[3] = __builtin_amdgcn_mfma_f32_16x16x32_bf16(ah, b3, acc[3], 0, 0, 0);
            acc[3] = __builtin_amdgcn_mfma_f32_16x16x32_bf16(al, b3, acc[3], 0, 0, 0);
        }
    }

    __syncthreads();                            // lg zeroed (and all waves done)

    // ---- K-reduction: ds_add_f32 into lg ----
    // C-layout per nt: col = nt*16 + (lane&15), row = (lane>>4)*4 + r
    {
        const int r0 = (lane >> 4) * 4;
        const int c  = lane & 15;
#pragma unroll
        for (int nt = 0; nt < 4; ++nt)
#pragma unroll
            for (int r = 0; r < 4; ++r)
                atomicAdd(&lg[r0 + r][nt * 16 + c], acc[nt][r]);
    }
    __syncthreads();                            // lg complete

    // ---- fused gate: each wave handles 2 tokens, lane = expert ----
    float ssum_l = 0.f;                         // per-expert softmax-score sum (2 tokens)

#pragma unroll
    for (int r = 0; r < 2; ++r) {
        const int tl = wavei * 2 + r;
        const int t  = tok0 + tl;
        float l = lg[tl][lane];

        // softmax score (fp32, feeds aux only)
        float mx = l;
#pragma unroll
        for (int off = 32; off; off >>= 1) mx = fmaxf(mx, __shfl_xor(mx, off, 64));
        float p = __expf(l - mx);
        float Z = p;
#pragma unroll
        for (int off = 32; off; off >>= 1) Z += __shfl_xor(Z, off, 64);
        ssum_l += p / Z;

        // top-3 by screened logit (tie -> lower index); cl[2] only feeds the flag
        float v = l;
        int cand[3]; float cl[3];
#pragma unroll
        for (int q = 0; q < 3; ++q) {
            float bv = v; int bi = lane;
#pragma unroll
            for (int off = 32; off; off >>= 1) {
                float ov = __shfl_xor(bv, off, 64);
                int   oi = __shfl_xor(bi, off, 64);
                if (ov > bv || (ov == bv && oi < bi)) { bv = ov; bi = oi; }
            }
            cand[q] = bi; cl[q] = bv;
            if (lane == bi) v = -3.4e38f;
        }

        if (lane == 0) {
            atomicAdd(&bcnt[cand[0]], 1.f);      // LDS atomics, trivial
            atomicAdd(&bcnt[cand[1]], 1.f);
            float w1 = 1.f / (1.f + __expf(cl[1] - cl[0]));  // softmax denom cancels
            out_idx[t * 2]     = (float)cand[0];
            out_idx[t * 2 + 1] = (float)cand[1];
            out_w[t * 2]       = w1;
            out_w[t * 2 + 1]   = 1.f - w1;
            if (cl[0] - cl[1] < TAU || cl[1] - cl[2] < TAU) {
                int pos = atomicAdd(&fl_cnt, 1);
                fl[pos] = tl;
            }
        }
    }

    atomicAdd(&bssum[lane], ssum_l);            // 8 waves -> LDS
    __syncthreads();                            // bcnt/bssum/fl complete

    // ---- publish per-block partials: ONE relaxed atomicAdd per expert ----
    {
        const int b   = tok0 >> 12;             // block-uniform batch index
        const int rep = (blockIdx.x & (NREP - 1)) * (BB * EE);
        if (tid < EE)
            atomicAdd(&g_cnt[rep + b * EE + tid], bcnt[tid]);
        else if (tid < 2 * EE)
            atomicAdd(&g_ssum[rep + b * EE + (tid - EE)], bssum[tid - EE]);
    }

    // ---- inline fp64 exact re-rank of this block's flagged tokens (~1.8/block) ----
    const int nfl = fl_cnt;
    for (int i = wavei; i < nfl; i += 8) {
        const int tl = fl[i];
        const int t  = tok0 + tl;
        float l = lg[tl][lane];

        float v = l;
        int cand4[4];
#pragma unroll
        for (int q = 0; q < 4; ++q) {
            float bv = v; int bi = lane;
#pragma unroll
            for (int off = 32; off; off >>= 1) {
                float ov = __shfl_xor(bv, off, 64);
                int   oi = __shfl_xor(bi, off, 64);
                if (ov > bv || (ov == bv && oi < bi)) { bv = ov; bi = oi; }
            }
            cand4[q] = bi;
            if (lane == bi) v = -3.4e38f;
        }

        const float* __restrict__ xt  = x + (size_t)t * HH;          // L2-hot
        const float* __restrict__ w0p = w + (size_t)cand4[0] * HH;
        const float* __restrict__ w1p = w + (size_t)cand4[1] * HH;
        const float* __restrict__ w2p = w + (size_t)cand4[2] * HH;
        const float* __restrict__ w3p = w + (size_t)cand4[3] * HH;
        double d0 = 0.0, d1 = 0.0, d2 = 0.0, d3 = 0.0;
#pragma unroll
        for (int ii = 0; ii < 8; ++ii) {
            const int k = ii * 256 + lane * 4;
            v4f xv = *(const v4f*)(xt + k);
            v4f a0 = *(const v4f*)(w0p + k);
            v4f a1 = *(const v4f*)(w1p + k);
            v4f a2 = *(const v4f*)(w2p + k);
            v4f a3 = *(const v4f*)(w3p + k);
            double dx0 = (double)xv.x, dx1 = (double)xv.y;
            double dx2 = (double)xv.z, dx3 = (double)xv.w;
            d0 = fma(dx0, (double)a0.x, d0); d0 = fma(dx1, (double)a0.y, d0);
            d0 = fma(dx2, (double)a0.z, d0); d0 = fma(dx3, (double)a0.w, d0);
            d1 = fma(dx0, (double)a1.x, d1); d1 = fma(dx1, (double)a1.y, d1);
            d1 = fma(dx2, (double)a1.z, d1); d1 = fma(dx3, (double)a1.w, d1);
            d2 = fma(dx0, (double)a2.x, d2); d2 = fma(dx1, (double)a2.y, d2);
            d2 = fma(dx2, (double)a2.z, d2); d2 = fma(dx3, (double)a2.w, d2);
            d3 = fma(dx0, (double)a3.x, d3); d3 = fma(dx1, (double)a3.y, d3);
            d3 = fma(dx2, (double)a3.z, d3); d3 = fma(dx3, (double)a3.w, d3);
        }
#pragma unroll
        for (int off = 32; off; off >>= 1) {
            d0 += __shfl_xor(d0, off, 64);
            d1 += __shfl_xor(d1, off, 64);
            d2 += __shfl_xor(d2, off, 64);
            d3 += __shfl_xor(d3, off, 64);
        }

        double bd[4] = {d0, d1, d2, d3};
        int e1 = cand4[0]; double l1 = bd[0];
#pragma unroll
        for (int q = 1; q < 4; ++q)
            if (bd[q] > l1 || (bd[q] == l1 && cand4[q] < e1)) { l1 = bd[q]; e1 = cand4[q]; }
        int e2 = -1; double l2 = -1e300;
#pragma unroll
        for (int q = 0; q < 4; ++q) {
            if (cand4[q] == e1) continue;
            if (e2 < 0 || bd[q] > l2 || (bd[q] == l2 && cand4[q] < e2)) { l2 = bd[q]; e2 = cand4[q]; }
        }

        double w1d = 1.0 / (1.0 + exp(l2 - l1));
        if (lane == 0) {
            out_idx[t * 2]     = (float)e1;
            out_idx[t * 2 + 1] = (float)e2;
            out_w[t * 2]       = (float)w1d;
            out_w[t * 2 + 1]   = (float)(1.0 - w1d);
        }
    }
}

// aux = 0.01/(B * 128 * S) * sum_{b,e} cnt[b,e]*ssum[b,e]   (E/(S*K)=1/128)
__global__ void finalize(const float* __restrict__ g_cnt,
                         const float* __restrict__ g_ssum,
                         float* __restrict__ aux_out) {
    int lane = threadIdx.x;  // 64 threads, lane = expert
    float a = 0.f;
    for (int b = 0; b < BB; ++b) {
        float c = 0.f, ss = 0.f;
#pragma unroll
        for (int r = 0; r < NREP; ++r) {
            c  += g_cnt[r * (BB * EE) + b * EE + lane];
            ss += g_ssum[r * (BB * EE) + b * EE + lane];
        }
        a += c * ss;
    }
#pragma unroll
    for (int off = 32; off; off >>= 1) a += __shfl_xor(a, off, 64);
    if (lane == 0) aux_out[0] = a * (0.01f / (4.f * 128.f * 4096.f));
}

extern "C" void kernel_launch(void* const* d_in, const int* in_sizes, int n_in,
                              void* d_out, int out_size, void* d_ws, size_t ws_size,
                              hipStream_t stream) {
    const float* x = (const float*)d_in[0];   // [4,4096,2048]
    const float* w = (const float*)d_in[1];   // [64,2048]
    float* out = (float*)d_out;
    float* out_idx = out;                 // [16384*2]
    float* out_w   = out + 2 * TT;        // [16384*2]
    float* aux     = out + 4 * TT;        // [1]

    // ws layout
    unsigned short* bhi = (unsigned short*)d_ws;                    // 256 KB
    float* g_cnt  = (float*)(bhi + (size_t)EE * HH);                // 8 KB
    float* g_ssum = g_cnt + NREP * BB * EE;                         // 8 KB

    prep_b<<<(EE * HH) / 256, 256, 0, stream>>>(w, bhi, g_cnt);
    gemm_gate<<<NBLK, 512, 0, stream>>>(x, bhi, w, out_idx, out_w,
                                        g_cnt, g_ssum);
    finalize<<<1, 64, 0, stream>>>(g_cnt, g_ssum, aux);
}

// Round 11
// 212.737 us; speedup vs baseline: 1.3435x; 1.2873x over previous
//
#include <hip/hip_runtime.h>
#include <math.h>

// MoE gate: B=4, S=4096, H=2048, E=64, top-2, seq_aux loss.
// d_out layout (float): topk_idx [16384*2] | topk_weight [16384*2] | aux_loss [1]
//
// v12: return to the PROVEN round-3 structure (best total 219.6us; LDS-staged A,
//  256 threads, dbuf, fused gate + inline fp64 rerank + replicated-atomic aux)
//  and apply the one validated improvement from rounds 7-10: the 2-TERM screen.
//  - A = ah + al (exact to 2^-16, staged in LDS as before); B = rounded bf16 ONLY
//    (blo deleted). Per ks-step: 2 MFMA + 1 B load (was 3 MFMA + 2 B loads).
//    B L2 traffic halves; prep_b halves.
//  - Screen error = x*dw only: gap sigma ~9.2e-4; TAU = 8e-3 = 8.7 sigma
//    (passed correctness in r8/r9/r10). fp64 re-rank absorbs flagged ~10-13%.
//  Launch-bounds lesson (v7-v11): tight 2nd arg -> allocator clamps+spills;
//  none -> under-occupies. Keep v4's plain __launch_bounds__(256), VGPR ~56-60.
//  K1 prep_b:    pack W to MFMA B-frags (bf16 rounded) + zero aux accums.
//  K2 gemm_gate: 2-term screening GEMM + fused gate/top-3/aux + inline fp64 rerank.
//  K3 finalize:  1 block, reduces replicated accumulators -> aux_loss.

#define TT 16384
#define HH 2048
#define EE 64
#define BB 4
#define M_TOK 16   // tokens per GEMM block
#define KCH 256    // k per LDS chunk
#define TAU 8e-3f  // gap threshold: 8.7 sigma of 2-term screening gap error
#define NREP 8     // atomic replication for aux accumulators
#define NBLK (TT / M_TOK)   // 1024

typedef float v4f __attribute__((ext_vector_type(4)));
typedef float f4v __attribute__((ext_vector_type(4)));
typedef short s8v __attribute__((ext_vector_type(8)));

__device__ __forceinline__ unsigned short f2bf(float f) {
    unsigned u = __float_as_uint(f);
    return (unsigned short)((u + 0x7fffu + ((u >> 16) & 1u)) >> 16);
}
__device__ __forceinline__ float bf2f(unsigned short h) {
    return __uint_as_float(((unsigned)h) << 16);
}

// Pre-pack W[E][H] into MFMA B-fragment order, bf16 (rounded):
// b[nt][ks][lane][j] = w[nt*16 + (lane&15)][ks*32 + (lane>>4)*8 + j]
// Block 0 also zeroes the replicated aux accumulators (stream order covers K2).
__global__ void prep_b(const float* __restrict__ w,
                       unsigned short* __restrict__ bhi,
                       float* __restrict__ zreg) {
    if (blockIdx.x == 0) {
        for (int i = threadIdx.x; i < 2 * NREP * BB * EE; i += 256) zreg[i] = 0.f;
    }
    int idx = blockIdx.x * blockDim.x + threadIdx.x;   // 0..131071
    int j    = idx & 7;
    int lane = (idx >> 3) & 63;
    int ks   = (idx >> 9) & 63;
    int nt   = idx >> 15;
    int e = nt * 16 + (lane & 15);
    int k = ks * 32 + (lane >> 4) * 8 + j;
    bhi[idx] = f2bf(w[e * HH + k]);
}

// ---------------- K2: MFMA GEMM (2-term screen) + gate + inline rerank ----------------
__global__ __launch_bounds__(256) void gemm_gate(
    const float* __restrict__ x,
    const unsigned short* __restrict__ bhi,
    const float* __restrict__ w,
    float* __restrict__ out_idx, float* __restrict__ out_w,
    float* __restrict__ g_cnt, float* __restrict__ g_ssum) {

    __shared__ unsigned short ahi[2][8 * 64 * 8];  // 2 x 8 KB (A hi, truncated)
    __shared__ unsigned short alo[2][8 * 64 * 8];  // 2 x 8 KB (A residual)
    __shared__ float lg[M_TOK][68];                // logit tile, padded
    __shared__ float bssum[EE];                    // per-expert score sums
    __shared__ float bcnt[EE];                     // per-expert top-2 counts
    __shared__ int   fl[M_TOK];                    // flagged-token list (local rows)
    __shared__ int   fl_cnt;

    const int tid  = threadIdx.x;
    const int wave = tid >> 6;                  // N-tile (16 experts)
    const int lane = tid & 63;
    const int tok0 = blockIdx.x * M_TOK;
    const int m  = tid >> 4;                    // staging token row 0..15
    const int kb = tid & 15;

    if (tid < EE) { bssum[tid] = 0.f; bcnt[tid] = 0.f; }
    if (tid == 0) fl_cnt = 0;

    v4f rx[2][4];                               // 2 chunks in flight, 16 floats each

    auto LD = [&](int c, int s) {
        const float* __restrict__ xp = x + (size_t)(tok0 + m) * HH + c * KCH + kb * 8;
        rx[s][0] = *(const v4f*)xp;
        rx[s][1] = *(const v4f*)(xp + 4);
        rx[s][2] = *(const v4f*)(xp + 128);
        rx[s][3] = *(const v4f*)(xp + 132);
    };
    auto ST = [&](int s, int bi) {
#pragma unroll
        for (int g = 0; g < 2; ++g) {
            v4f a = rx[s][g * 2], b2 = rx[s][g * 2 + 1];
            float xs[8] = {a.x, a.y, a.z, a.w, b2.x, b2.y, b2.z, b2.w};
            s8v hv, lv;
#pragma unroll
            for (int j = 0; j < 8; ++j) {
                unsigned u = __float_as_uint(xs[j]);
                unsigned mhi = u & 0xffff0000u;
                hv[j] = (short)(u >> 16);                       // truncated hi
                float lo = xs[j] - __uint_as_float(mhi);        // exact residual
                lv[j] = (short)(__float_as_uint(lo) >> 16);
            }
            const int k8i = kb + g * 16;
            const int kstep = k8i >> 2, quad = k8i & 3;
            const int entry = kstep * 64 + quad * 16 + (m ^ (quad << 1)); // swizzle
            *(s8v*)&ahi[bi][entry * 8] = hv;
            *(s8v*)&alo[bi][entry * 8] = lv;
        }
    };

    LD(0, 0);
    LD(1, 1);
    ST(0, 0);
    __syncthreads();

    f4v acc = {0.f, 0.f, 0.f, 0.f};
    const int rdl = lane ^ ((lane >> 4) << 1);  // swizzled read lane

#pragma unroll
    for (int c = 0; c < 8; ++c) {
        const int cur = c & 1;
        if (c < 6) LD(c + 2, cur);              // prefetch 2 chunks ahead
        if (c < 7) ST(cur ^ 1, cur ^ 1);        // stage chunk c+1 into other buffer
#pragma unroll
        for (int ks = 0; ks < 8; ++ks) {
            const int entry = ks * 64 + rdl;
            s8v af_h = *(const s8v*)&ahi[cur][entry * 8];
            s8v af_l = *(const s8v*)&alo[cur][entry * 8];
            const size_t boff = ((size_t)(wave * 64 + c * 8 + ks) * 64 + lane) * 8;
            s8v bf_h = *(const s8v*)&bhi[boff];
            acc = __builtin_amdgcn_mfma_f32_16x16x32_bf16(af_h, bf_h, acc, 0, 0, 0);
            acc = __builtin_amdgcn_mfma_f32_16x16x32_bf16(af_l, bf_h, acc, 0, 0, 0);
        }
        __syncthreads();                        // one barrier per chunk (dbuf)
    }

    // C-layout: col = lane&15 (expert in tile), row = (lane>>4)*4 + r (token)
#pragma unroll
    for (int r = 0; r < 4; ++r) {
        const int row = (lane >> 4) * 4 + r;
        const int col = wave * 16 + (lane & 15);
        lg[row][col] = acc[r];
    }
    __syncthreads();

    // ---- fused gate: each wave handles 4 tokens, lane = expert ----
    float ssum_l = 0.f;                         // per-expert softmax-score sum (4 tokens)

#pragma unroll
    for (int r = 0; r < 4; ++r) {
        const int tl = wave * 4 + r;
        const int t  = tok0 + tl;
        float l = lg[tl][lane];

        // softmax score (fp32, feeds aux only)
        float mx = l;
#pragma unroll
        for (int off = 32; off; off >>= 1) mx = fmaxf(mx, __shfl_xor(mx, off, 64));
        float p = __expf(l - mx);
        float Z = p;
#pragma unroll
        for (int off = 32; off; off >>= 1) Z += __shfl_xor(Z, off, 64);
        ssum_l += p / Z;

        // top-3 by screened logit (tie -> lower index); cl[2] only feeds the flag
        float v = l;
        int cand[3]; float cl[3];
#pragma unroll
        for (int q = 0; q < 3; ++q) {
            float bv = v; int bi = lane;
#pragma unroll
            for (int off = 32; off; off >>= 1) {
                float ov = __shfl_xor(bv, off, 64);
                int   oi = __shfl_xor(bi, off, 64);
                if (ov > bv || (ov == bv && oi < bi)) { bv = ov; bi = oi; }
            }
            cand[q] = bi; cl[q] = bv;
            if (lane == bi) v = -3.4e38f;
        }

        if (lane == 0) {
            atomicAdd(&bcnt[cand[0]], 1.f);      // LDS atomics, trivial
            atomicAdd(&bcnt[cand[1]], 1.f);
            float w1 = 1.f / (1.f + __expf(cl[1] - cl[0]));  // softmax denom cancels
            out_idx[t * 2]     = (float)cand[0];
            out_idx[t * 2 + 1] = (float)cand[1];
            out_w[t * 2]       = w1;
            out_w[t * 2 + 1]   = 1.f - w1;
            if (cl[0] - cl[1] < TAU || cl[1] - cl[2] < TAU) {
                int pos = atomicAdd(&fl_cnt, 1);
                fl[pos] = tl;
            }
        }
    }

    atomicAdd(&bssum[lane], ssum_l);            // 4 waves -> LDS
    __syncthreads();                            // bcnt/bssum/fl complete

    // ---- publish per-block partials: ONE relaxed atomicAdd per expert ----
    {
        const int b   = tok0 >> 12;             // block-uniform batch index
        const int rep = (blockIdx.x & (NREP - 1)) * (BB * EE);
        if (tid < EE)
            atomicAdd(&g_cnt[rep + b * EE + tid], bcnt[tid]);
        else if (tid < 2 * EE)
            atomicAdd(&g_ssum[rep + b * EE + (tid - EE)], bssum[tid - EE]);
    }

    // ---- inline fp64 exact re-rank of this block's flagged tokens (~1.8/block) ----
    const int nfl = fl_cnt;
    for (int i = wave; i < nfl; i += 4) {
        const int tl = fl[i];
        const int t  = tok0 + tl;
        float l = lg[tl][lane];

        float v = l;
        int cand4[4];
#pragma unroll
        for (int q = 0; q < 4; ++q) {
            float bv = v; int bi = lane;
#pragma unroll
            for (int off = 32; off; off >>= 1) {
                float ov = __shfl_xor(bv, off, 64);
                int   oi = __shfl_xor(bi, off, 64);
                if (ov > bv || (ov == bv && oi < bi)) { bv = ov; bi = oi; }
            }
            cand4[q] = bi;
            if (lane == bi) v = -3.4e38f;
        }

        const float* __restrict__ xt  = x + (size_t)t * HH;          // L2-hot
        const float* __restrict__ w0p = w + (size_t)cand4[0] * HH;
        const float* __restrict__ w1p = w + (size_t)cand4[1] * HH;
        const float* __restrict__ w2p = w + (size_t)cand4[2] * HH;
        const float* __restrict__ w3p = w + (size_t)cand4[3] * HH;
        double d0 = 0.0, d1 = 0.0, d2 = 0.0, d3 = 0.0;
#pragma unroll
        for (int ii = 0; ii < 8; ++ii) {
            const int k = ii * 256 + lane * 4;
            v4f xv = *(const v4f*)(xt + k);
            v4f a0 = *(const v4f*)(w0p + k);
            v4f a1 = *(const v4f*)(w1p + k);
            v4f a2 = *(const v4f*)(w2p + k);
            v4f a3 = *(const v4f*)(w3p + k);
            double dx0 = (double)xv.x, dx1 = (double)xv.y;
            double dx2 = (double)xv.z, dx3 = (double)xv.w;
            d0 = fma(dx0, (double)a0.x, d0); d0 = fma(dx1, (double)a0.y, d0);
            d0 = fma(dx2, (double)a0.z, d0); d0 = fma(dx3, (double)a0.w, d0);
            d1 = fma(dx0, (double)a1.x, d1); d1 = fma(dx1, (double)a1.y, d1);
            d1 = fma(dx2, (double)a1.z, d1); d1 = fma(dx3, (double)a1.w, d1);
            d2 = fma(dx0, (double)a2.x, d2); d2 = fma(dx1, (double)a2.y, d2);
            d2 = fma(dx2, (double)a2.z, d2); d2 = fma(dx3, (double)a2.w, d2);
            d3 = fma(dx0, (double)a3.x, d3); d3 = fma(dx1, (double)a3.y, d3);
            d3 = fma(dx2, (double)a3.z, d3); d3 = fma(dx3, (double)a3.w, d3);
        }
#pragma unroll
        for (int off = 32; off; off >>= 1) {
            d0 += __shfl_xor(d0, off, 64);
            d1 += __shfl_xor(d1, off, 64);
            d2 += __shfl_xor(d2, off, 64);
            d3 += __shfl_xor(d3, off, 64);
        }

        double bd[4] = {d0, d1, d2, d3};
        int e1 = cand4[0]; double l1 = bd[0];
#pragma unroll
        for (int q = 1; q < 4; ++q)
            if (bd[q] > l1 || (bd[q] == l1 && cand4[q] < e1)) { l1 = bd[q]; e1 = cand4[q]; }
        int e2 = -1; double l2 = -1e300;
#pragma unroll
        for (int q = 0; q < 4; ++q) {
            if (cand4[q] == e1) continue;
            if (e2 < 0 || bd[q] > l2 || (bd[q] == l2 && cand4[q] < e2)) { l2 = bd[q]; e2 = cand4[q]; }
        }

        double w1d = 1.0 / (1.0 + exp(l2 - l1));
        if (lane == 0) {
            out_idx[t * 2]     = (float)e1;
            out_idx[t * 2 + 1] = (float)e2;
            out_w[t * 2]       = (float)w1d;
            out_w[t * 2 + 1]   = (float)(1.0 - w1d);
        }
    }
}

// aux = 0.01/(B * 128 * S) * sum_{b,e} cnt[b,e]*ssum[b,e]   (E/(S*K)=1/128)
__global__ void finalize(const float* __restrict__ g_cnt,
                         const float* __restrict__ g_ssum,
                         float* __restrict__ aux_out) {
    int lane = threadIdx.x;  // 64 threads, lane = expert
    float a = 0.f;
    for (int b = 0; b < BB; ++b) {
        float c = 0.f, ss = 0.f;
#pragma unroll
        for (int r = 0; r < NREP; ++r) {
            c  += g_cnt[r * (BB * EE) + b * EE + lane];
            ss += g_ssum[r * (BB * EE) + b * EE + lane];
        }
        a += c * ss;
    }
#pragma unroll
    for (int off = 32; off; off >>= 1) a += __shfl_xor(a, off, 64);
    if (lane == 0) aux_out[0] = a * (0.01f / (4.f * 128.f * 4096.f));
}

extern "C" void kernel_launch(void* const* d_in, const int* in_sizes, int n_in,
                              void* d_out, int out_size, void* d_ws, size_t ws_size,
                              hipStream_t stream) {
    const float* x = (const float*)d_in[0];   // [4,4096,2048]
    const float* w = (const float*)d_in[1];   // [64,2048]
    float* out = (float*)d_out;
    float* out_idx = out;                 // [16384*2]
    float* out_w   = out + 2 * TT;        // [16384*2]
    float* aux     = out + 4 * TT;        // [1]

    // ws layout
    unsigned short* bhi = (unsigned short*)d_ws;                    // 256 KB
    float* g_cnt  = (float*)(bhi + (size_t)EE * HH);                // 8 KB
    float* g_ssum = g_cnt + NREP * BB * EE;                         // 8 KB

    prep_b<<<(EE * HH) / 256, 256, 0, stream>>>(w, bhi, g_cnt);
    gemm_gate<<<NBLK, 256, 0, stream>>>(x, bhi, w, out_idx, out_w,
                                        g_cnt, g_ssum);
    finalize<<<1, 64, 0, stream>>>(g_cnt, g_ssum, aux);
}